// Round 5
// baseline (746.913 us; speedup 1.0000x reference)
//
#include <hip/hip_runtime.h>
#include <hip/hip_bf16.h>

typedef short bf16x8 __attribute__((ext_vector_type(8)));
typedef float f32x4 __attribute__((ext_vector_type(4)));
typedef __attribute__((address_space(1))) const void gconst_t;
typedef __attribute__((address_space(3))) void lds_t;

#define DEVI __device__ __forceinline__

constexpr int BATCH   = 8192;
constexpr int IN_DIM  = 1024;
constexpr int HID     = 4096;
constexpr int OUT_DIM = 1024;
constexpr int NE      = 3;

// ---- workspace layout (bytes) ----
constexpr size_t XBF_OFF  = 0;                         // x bf16: 16 MB
constexpr size_t W1T_OFF  = 16777216;                  // W1T bf16 [E][HID][IN]: 24 MB
constexpr size_t W2T_OFF  = W1T_OFF + 25165824;        // W2T bf16 [E][OUT][HID]: 24 MB
constexpr size_t H_OFF    = W2T_OFF + 25165824;        // H bf16 grouped rows: 64 MB
constexpr size_t META_OFF = H_OFF + 67108864;          // counts[16], toklist[3*8192]

DEVI unsigned short f2bf(float f) {
  __hip_bfloat16 h = __float2bfloat16(f);
  return *reinterpret_cast<unsigned short*>(&h);
}

// =====================================================================
// Router: 512 blocks x 16 tokens, f32, VALU-bound design.
// rw1 staged in LDS in 64-k chunks; chunk c+1's global loads issued into
// registers while chunk c's FMAs run (T14 async-stage split). Weight reads
// are conflict-free ds_read_b32; x reads are wave-uniform LDS broadcasts.
// FMA order per (token,hcol): k ascending 0..1023 == rounds 1-4 (bit-exact).
// Emits toklist + counts (bucket fused, 16 lanes).
// =====================================================================
__global__ __launch_bounds__(256) void router_kernel(
    const float* __restrict__ x, const float* __restrict__ rw1, const float* __restrict__ rb1,
    const float* __restrict__ rw2, const float* __restrict__ rb2,
    int* __restrict__ counts, int* __restrict__ toklist) {
  __shared__ float wbuf[64][128];   // 32 KB: weight chunk [kk][hcol]
  __shared__ float xbuf[16][64];    // 4 KB:  x chunk [tok][kk]
  const int tid = threadIdx.x;
  const int t0 = blockIdx.x * 16;
  const int hcol = tid & 127;
  const int g = tid >> 7;           // wave-uniform: tokens g*8 .. g*8+7

  float acc[8] = {0.f, 0.f, 0.f, 0.f, 0.f, 0.f, 0.f, 0.f};
  float4 wA[8], wB[8], xA, xB;

  auto LD = [&](int c, float4* wr, float4& xr) {
    const int k0 = c * 64;
#pragma unroll
    for (int j = 0; j < 8; j++) {
      const int idx = tid + j * 256;                 // [0,2048)
      wr[j] = *(const float4*)&rw1[(size_t)(k0 + (idx >> 5)) * 128 + (idx & 31) * 4];
    }
    xr = *(const float4*)&x[(size_t)(t0 + (tid >> 4)) * 1024 + k0 + (tid & 15) * 4];
  };
  auto ST = [&](const float4* wr, const float4& xr) {
    float4* wl = (float4*)&wbuf[0][0];
#pragma unroll
    for (int j = 0; j < 8; j++) wl[tid + j * 256] = wr[j];
    ((float4*)&xbuf[0][0])[tid] = xr;
  };
  auto FMA_CHUNK = [&]() {
    for (int kk = 0; kk < 64; kk += 4) {
      const float w0 = wbuf[kk + 0][hcol];
      const float w1v = wbuf[kk + 1][hcol];
      const float w2v = wbuf[kk + 2][hcol];
      const float w3v = wbuf[kk + 3][hcol];
#pragma unroll
      for (int tt = 0; tt < 8; tt++) {
        const float4 xv = *(const float4*)&xbuf[g * 8 + tt][kk];
        acc[tt] = fmaf(xv.x, w0, acc[tt]);
        acc[tt] = fmaf(xv.y, w1v, acc[tt]);
        acc[tt] = fmaf(xv.z, w2v, acc[tt]);
        acc[tt] = fmaf(xv.w, w3v, acc[tt]);
      }
    }
  };

  LD(0, wA, xA);
  for (int c = 0; c < 16; c += 2) {
    __syncthreads();                       // prior chunk's LDS reads done
    ST(wA, xA);
    LD(c + 1, wB, xB);                     // in flight under FMA
    __syncthreads();
    FMA_CHUNK();
    __syncthreads();
    ST(wB, xB);
    if (c + 2 < 16) LD(c + 2, wA, xA);
    __syncthreads();
    FMA_CHUNK();
  }

  // layer 2 + argmax + bucket. rh aliases wbuf, lg aliases xbuf (both dead).
  __syncthreads();
  float* rh = &wbuf[0][0];                 // [16][132]
  const float bb1 = rb1[hcol];
#pragma unroll
  for (int tt = 0; tt < 8; tt++)
    rh[(g * 8 + tt) * 132 + hcol] = fmaxf(acc[tt] + bb1, 0.f);
  __syncthreads();
  float* lg = &xbuf[0][0];                 // [16][3]
  if (tid < 48) {
    const int t = tid / 3, e = tid % 3;
    float s = rb2[e];
    for (int j = 0; j < 128; j++) s = fmaf(rh[t * 132 + j], rw2[j * 3 + e], s);
    lg[t * 3 + e] = s;
  }
  __syncthreads();
  if (tid < 16) {
    const float l0 = lg[tid * 3], l1 = lg[tid * 3 + 1], l2 = lg[tid * 3 + 2];
    int sel = 0; float m = l0;
    if (l1 > m) { m = l1; sel = 1; }
    if (l2 > m) { m = l2; sel = 2; }
    const int slot = atomicAdd(&counts[sel], 1);
    toklist[sel * BATCH + slot] = t0 + tid;
  }
}

// =====================================================================
// prep2: weight transpose+cvt and x->bf16. 16.6 KB LDS -> ~9 blocks/CU.
//   [0,3072)      transpose+cvt W1 (per expert [1024][4096]->[4096][1024])
//   [3072,6144)   transpose+cvt W2 (per expert [4096][1024]->[1024][4096])
//   [6144,6656)   x f32 -> bf16
// =====================================================================
__global__ __launch_bounds__(256) void prep2_kernel(
    const float* __restrict__ x, const float* __restrict__ ew1, const float* __restrict__ ew2,
    unsigned short* __restrict__ xb, unsigned short* __restrict__ w1t,
    unsigned short* __restrict__ w2t) {
  __shared__ float tile[64][65];
  const int b = blockIdx.x;
  const int tid = threadIdx.x;

  if (b < 6144) {
    const float* src; unsigned short* dst; int R, C, r0, c0;
    if (b < 3072) {
      const int e = b / 1024, w = b % 1024;
      src = ew1 + (size_t)e * 1024 * 4096; dst = w1t + (size_t)e * 4096 * 1024;
      R = 1024; C = 4096; r0 = (w & 15) * 64; c0 = (w >> 4) * 64;
    } else {
      const int bb = b - 3072, e = bb / 1024, w = bb % 1024;
      src = ew2 + (size_t)e * 4096 * 1024; dst = w2t + (size_t)e * 1024 * 4096;
      R = 4096; C = 1024; r0 = (w & 63) * 64; c0 = (w >> 6) * 64;
    }
    const int tr = tid >> 4;
    const int tc = (tid & 15) << 2;
#pragma unroll
    for (int i = 0; i < 4; i++) {
      const int r = tr + i * 16;
      const float4 v = *(const float4*)(src + (size_t)(r0 + r) * C + (c0 + tc));
      tile[r][tc + 0] = v.x; tile[r][tc + 1] = v.y; tile[r][tc + 2] = v.z; tile[r][tc + 3] = v.w;
    }
    __syncthreads();
#pragma unroll
    for (int i = 0; i < 4; i++) {
      const int c = tr + i * 16;
      ushort4 o;
      o.x = f2bf(tile[tc + 0][c]);
      o.y = f2bf(tile[tc + 1][c]);
      o.z = f2bf(tile[tc + 2][c]);
      o.w = f2bf(tile[tc + 3][c]);
      *(ushort4*)(dst + (size_t)(c0 + c) * R + (r0 + tc)) = o;
    }
  } else {
    const float4* xv4 = (const float4*)x;
    const int total = BATCH * IN_DIM / 4;
    for (int i = (b - 6144) * 256 + tid; i < total; i += 512 * 256) {
      const float4 v = xv4[i];
      ushort4 o;
      o.x = f2bf(v.x); o.y = f2bf(v.y); o.z = f2bf(v.z); o.w = f2bf(v.w);
      ((ushort4*)xb)[i] = o;
    }
  }
}

// =====================================================================
// Grouped bf16 GEMM: BM=128, BN=256, BK=32, 8 waves (2M x 4N), 64x64/wave.
// Counted-vmcnt pipeline: NBUF=3, depth D=2, one s_barrier per K-step,
// steady-state s_waitcnt vmcnt(3), vmcnt(0) only at the final iteration.
// (unchanged from round 4 — it moved GEMMs below prep in the profile)
// =====================================================================
template <int MODE>
__global__ __launch_bounds__(512, 2) void moe_gemm(
    const unsigned short* __restrict__ Abase, const unsigned short* __restrict__ Ball,
    const float* __restrict__ biasAll, unsigned short* __restrict__ Hout,
    float* __restrict__ Yout, const int* __restrict__ toklist, const int* __restrict__ counts,
    float* __restrict__ tail) {
  constexpr int N  = (MODE == 0) ? HID : OUT_DIM;
  constexpr int K  = (MODE == 0) ? IN_DIM : HID;
  constexpr int NT = K / 32;

  const int tid = threadIdx.x;
  if (MODE == 0 && blockIdx.x == 0 && blockIdx.y == 0 && tid < NE)
    tail[tid] = (float)counts[tid];

  const int c0 = counts[0], c1 = counts[1], c2 = counts[2];
  const int mb0 = (c0 + 127) >> 7, mb1 = (c1 + 127) >> 7, mb2 = (c2 + 127) >> 7;
  const int bx = blockIdx.x;
  int e, mblk;
  if (bx < mb0) { e = 0; mblk = bx; }
  else if (bx < mb0 + mb1) { e = 1; mblk = bx - mb0; }
  else if (bx < mb0 + mb1 + mb2) { e = 2; mblk = bx - mb0 - mb1; }
  else return;
  const int cnt = (e == 0) ? c0 : (e == 1) ? c1 : c2;
  const int m0 = mblk * 128;
  const int n0 = blockIdx.y * 256;
  const int off_e = (e > 0 ? c0 : 0) + (e > 1 ? c1 : 0);
  const unsigned short* Bmat = Ball + (size_t)e * ((size_t)N * K);
  const float* bias = biasAll + (size_t)e * N;

  __shared__ unsigned short Ab[3][128 * 32];   // 8 KB per buf
  __shared__ unsigned short Bb[3][256 * 32];   // 16 KB per buf   (total 72 KB)

  const unsigned short* asrc;
  const unsigned short* bsrc[2];
  unsigned aoff, boff[2];
  {
    const unsigned o = (unsigned)tid * 16u;
    const unsigned p = o ^ (((o >> 6) & 3u) << 4);
    const int row = (int)(o >> 6);
    const int kel = (int)((p & 63u) >> 1);
    aoff = o;
    int slot = m0 + row; if (slot > cnt - 1) slot = cnt - 1;
    const size_t arow = (MODE == 0) ? (size_t)toklist[e * BATCH + slot]
                                    : (size_t)(off_e + slot);
    asrc = Abase + arow * K + kel;
  }
#pragma unroll
  for (int l = 0; l < 2; l++) {
    const unsigned o = l * 8192u + (unsigned)tid * 16u;
    const unsigned p = o ^ (((o >> 6) & 3u) << 4);
    const int row = (int)(o >> 6);
    const int kel = (int)((p & 63u) >> 1);
    boff[l] = o;
    bsrc[l] = Bmat + (size_t)(n0 + row) * K + kel;
  }

  f32x4 acc[4][4];
#pragma unroll
  for (int i = 0; i < 4; i++)
#pragma unroll
    for (int j = 0; j < 4; j++) acc[i][j] = {0.f, 0.f, 0.f, 0.f};

  const int lane = tid & 63;
  const int wave = tid >> 6;
  const int wm = (wave >> 2) * 64;
  const int wn = (wave & 3) * 64;
  const int fr = lane & 15;
  const int fc = lane >> 4;

  auto STAGE = [&](int buf, int kofs) {
    __builtin_amdgcn_global_load_lds((gconst_t*)(asrc + kofs),
                                     (lds_t*)((char*)&Ab[buf][0] + aoff), 16, 0, 0);
#pragma unroll
    for (int l = 0; l < 2; l++)
      __builtin_amdgcn_global_load_lds((gconst_t*)(bsrc[l] + kofs),
                                       (lds_t*)((char*)&Bb[buf][0] + boff[l]), 16, 0, 0);
  };

  STAGE(0, 0);
  STAGE(1, 32);

  int cur = 0;
  for (int t = 0; t < NT; ++t) {
    if (t + 1 < NT) asm volatile("s_waitcnt vmcnt(3)" ::: "memory");
    else            asm volatile("s_waitcnt vmcnt(0)" ::: "memory");
    __builtin_amdgcn_sched_barrier(0);
    __builtin_amdgcn_s_barrier();          // all waves' stage-t landed
    __builtin_amdgcn_sched_barrier(0);
    bf16x8 af[4], bv[4];
#pragma unroll
    for (int m = 0; m < 4; m++) {
      const unsigned row = (unsigned)(wm + m * 16 + fr);
      const unsigned addr = ((row << 6) + (unsigned)(fc << 4)) ^ ((row & 3u) << 4);
      af[m] = *(const bf16x8*)((const char*)&Ab[cur][0] + addr);
    }
#pragma unroll
    for (int n = 0; n < 4; n++) {
      const unsigned row = (unsigned)(wn + n * 16 + fr);
      const unsigned addr = ((row << 6) + (unsigned)(fc << 4)) ^ ((row & 3u) << 4);
      bv[n] = *(const bf16x8*)((const char*)&Bb[cur][0] + addr);
    }
    asm volatile("s_waitcnt lgkmcnt(0)" ::: "memory");
    __builtin_amdgcn_sched_barrier(0);     // rule #18: pin MFMA after the wait
    __builtin_amdgcn_s_setprio(1);
#pragma unroll
    for (int m = 0; m < 4; m++)
#pragma unroll
      for (int n = 0; n < 4; n++)
        acc[m][n] = __builtin_amdgcn_mfma_f32_16x16x32_bf16(af[m], bv[n], acc[m][n], 0, 0, 0);
    __builtin_amdgcn_s_setprio(0);
    if (t + 2 < NT) {
      const int nb = (cur + 2 >= 3) ? cur - 1 : cur + 2;
      STAGE(nb, (t + 2) * 32);
    }
    cur = (cur + 1 == 3) ? 0 : cur + 1;
  }

  // epilogue: C/D layout col=lane&15, row=(lane>>4)*4+reg  [HW-verified m89/m91]
  const int crow = (lane >> 4) * 4;
  const int ccol = lane & 15;
#pragma unroll
  for (int mi = 0; mi < 4; mi++) {
#pragma unroll
    for (int r = 0; r < 4; r++) {
      const int slot = m0 + wm + mi * 16 + crow + r;
      if (slot >= cnt) continue;
      if (MODE == 0) {
        unsigned short* hrow = Hout + (size_t)(off_e + slot) * HID;
#pragma unroll
        for (int ni = 0; ni < 4; ni++) {
          const int n = n0 + wn + ni * 16 + ccol;
          const float v = acc[mi][ni][r] + bias[n];
          hrow[n] = f2bf(fmaxf(v, 0.f));
        }
      } else {
        const int tok = toklist[e * BATCH + slot];
        float* yrow = Yout + (size_t)tok * OUT_DIM;
#pragma unroll
        for (int ni = 0; ni < 4; ni++) {
          const int n = n0 + wn + ni * 16 + ccol;
          yrow[n] = acc[mi][ni][r] + bias[n];
        }
      }
    }
  }
}

extern "C" void kernel_launch(void* const* d_in, const int* in_sizes, int n_in,
                              void* d_out, int out_size, void* d_ws, size_t ws_size,
                              hipStream_t stream) {
  const float* x   = (const float*)d_in[0];
  const float* rw1 = (const float*)d_in[1];
  const float* rb1 = (const float*)d_in[2];
  const float* rw2 = (const float*)d_in[3];
  const float* rb2 = (const float*)d_in[4];
  const float* ew1 = (const float*)d_in[5];
  const float* eb1 = (const float*)d_in[6];
  const float* ew2 = (const float*)d_in[7];
  const float* eb2 = (const float*)d_in[8];
  float* out = (float*)d_out;

  char* ws = (char*)d_ws;
  unsigned short* xb  = (unsigned short*)(ws + XBF_OFF);
  unsigned short* w1t = (unsigned short*)(ws + W1T_OFF);
  unsigned short* w2t = (unsigned short*)(ws + W2T_OFF);
  unsigned short* h   = (unsigned short*)(ws + H_OFF);
  int* counts  = (int*)(ws + META_OFF);
  int* toklist = counts + 16;
  float* tail = out + (size_t)BATCH * OUT_DIM;

  hipMemsetAsync(counts, 0, 64, stream);
  router_kernel<<<512, 256, 0, stream>>>(x, rw1, rb1, rw2, rb2, counts, toklist);
  prep2_kernel<<<6656, 256, 0, stream>>>(x, ew1, ew2, xb, w1t, w2t);
  moe_gemm<0><<<dim3(66, 16), 512, 0, stream>>>(xb, w1t, eb1, h, nullptr, toklist, counts, tail);
  moe_gemm<1><<<dim3(66, 4), 512, 0, stream>>>(h, w2t, eb2, nullptr, out, toklist, counts, tail);
}

// Round 6
// 394.392 us; speedup vs baseline: 1.8938x; 1.8938x over previous
//
#include <hip/hip_runtime.h>
#include <hip/hip_bf16.h>

typedef short bf16x8 __attribute__((ext_vector_type(8)));
typedef float f32x4 __attribute__((ext_vector_type(4)));
typedef __attribute__((address_space(1))) const void gconst_t;
typedef __attribute__((address_space(3))) void lds_t;

#define DEVI __device__ __forceinline__

constexpr int BATCH   = 8192;
constexpr int IN_DIM  = 1024;
constexpr int HID     = 4096;
constexpr int OUT_DIM = 1024;
constexpr int NE      = 3;

// ---- workspace layout (bytes) ----
constexpr size_t XBF_OFF  = 0;                         // x bf16: 16 MB
constexpr size_t W1T_OFF  = 16777216;                  // W1T bf16 [E][HID][IN]: 24 MB
constexpr size_t W2T_OFF  = W1T_OFF + 25165824;        // W2T bf16 [E][OUT][HID]: 24 MB
constexpr size_t H_OFF    = W2T_OFF + 25165824;        // H bf16 grouped rows: 64 MB
constexpr size_t META_OFF = H_OFF + 67108864;          // counts[16], toklist[3*8192]

DEVI unsigned short f2bf(float f) {
  __hip_bfloat16 h = __float2bfloat16(f);
  return *reinterpret_cast<unsigned short*>(&h);
}

// =====================================================================
// Router: 512 blocks x 16 tokens, f32. NO register staging (round-5 spill
// post-mortem: arrays-by-pointer -> scratch, 752 MB spill traffic).
// rw1 chunks (contiguous 32 KB) + x chunks staged straight into LDS via
// global_load_lds, double-buffered, minimum-2-phase loop:
//   vmcnt(0) -> s_barrier -> STAGE(c+1) -> FMA(c)
// WAR: STAGE(c+1) writes buf[(c+1)&1], last read by FMA(c-1), which all
// waves finished before this iteration's barrier. FMA order per
// (token,hcol): k ascending, x/y/z/w — bit-identical to rounds 1-4.
// =====================================================================
__global__ __launch_bounds__(256) void router_kernel(
    const float* __restrict__ x, const float* __restrict__ rw1, const float* __restrict__ rb1,
    const float* __restrict__ rw2, const float* __restrict__ rb2,
    int* __restrict__ counts, int* __restrict__ toklist) {
  __shared__ float wbuf[2][64 * 128];   // 64 KB: weight chunk [kk][hcol]
  __shared__ float xbuf[2][16 * 64];    // 8 KB:  x chunk [tok][kk]
  const int tid = threadIdx.x;
  const int t0 = blockIdx.x * 16;
  const int hcol = tid & 127;
  const int g = tid >> 7;               // wave-uniform: tokens g*8 .. g*8+7

  // stage sources: rw1 chunk c = floats [c*8192, c*8192+8192) (contiguous);
  // x chunk c = 16 rows x 64 floats (256 B/row, per-lane addresses).
  const float* wsrc = rw1 + (size_t)tid * 4;
  const float* xsrc = x + (size_t)(t0 + (tid >> 4)) * 1024 + (tid & 15) * 4;
  const unsigned soff = (unsigned)tid * 16u;   // LDS byte offset (linear fill)

  auto STAGE = [&](int buf, int c) {
#pragma unroll
    for (int j = 0; j < 8; j++)
      __builtin_amdgcn_global_load_lds((gconst_t*)(wsrc + (size_t)c * 8192 + j * 1024),
                                       (lds_t*)((char*)&wbuf[buf][0] + j * 4096 + soff), 16, 0, 0);
    __builtin_amdgcn_global_load_lds((gconst_t*)(xsrc + c * 64),
                                     (lds_t*)((char*)&xbuf[buf][0] + soff), 16, 0, 0);
  };

  float acc[8] = {0.f, 0.f, 0.f, 0.f, 0.f, 0.f, 0.f, 0.f};

  STAGE(0, 0);
  for (int c = 0; c < 16; ++c) {
    asm volatile("s_waitcnt vmcnt(0)" ::: "memory");   // my stage-c landed
    __builtin_amdgcn_sched_barrier(0);
    __builtin_amdgcn_s_barrier();                      // everyone's stage-c landed; FMA(c-1) done
    __builtin_amdgcn_sched_barrier(0);
    if (c + 1 < 16) STAGE((c + 1) & 1, c + 1);         // in flight under FMA(c)
    const float* wb = &wbuf[c & 1][0];
    const float* xb = &xbuf[c & 1][0];
    for (int kk = 0; kk < 64; kk += 4) {
      const float w0 = wb[(kk + 0) * 128 + hcol];
      const float w1v = wb[(kk + 1) * 128 + hcol];
      const float w2v = wb[(kk + 2) * 128 + hcol];
      const float w3v = wb[(kk + 3) * 128 + hcol];
#pragma unroll
      for (int tt = 0; tt < 8; tt++) {
        const float4 xv = *(const float4*)&xb[(g * 8 + tt) * 64 + kk];
        acc[tt] = fmaf(xv.x, w0, acc[tt]);
        acc[tt] = fmaf(xv.y, w1v, acc[tt]);
        acc[tt] = fmaf(xv.z, w2v, acc[tt]);
        acc[tt] = fmaf(xv.w, w3v, acc[tt]);
      }
    }
  }

  // layer 2 + argmax + bucket. rh aliases wbuf[0], lg aliases xbuf[0]
  // (both regions dead: last used at chunk 14; FMA(15) reads buf 1).
  __syncthreads();
  float* rh = &wbuf[0][0];                 // [16][132]
  const float bb1 = rb1[hcol];
#pragma unroll
  for (int tt = 0; tt < 8; tt++)
    rh[(g * 8 + tt) * 132 + hcol] = fmaxf(acc[tt] + bb1, 0.f);
  __syncthreads();
  float* lg = &xbuf[0][0];                 // [16][3]
  if (tid < 48) {
    const int t = tid / 3, e = tid % 3;
    float s = rb2[e];
    for (int j = 0; j < 128; j++) s = fmaf(rh[t * 132 + j], rw2[j * 3 + e], s);
    lg[t * 3 + e] = s;
  }
  __syncthreads();
  if (tid < 16) {
    const float l0 = lg[tid * 3], l1 = lg[tid * 3 + 1], l2 = lg[tid * 3 + 2];
    int sel = 0; float m = l0;
    if (l1 > m) { m = l1; sel = 1; }
    if (l2 > m) { m = l2; sel = 2; }
    const int slot = atomicAdd(&counts[sel], 1);
    toklist[sel * BATCH + slot] = t0 + tid;
  }
}

// =====================================================================
// prep2: weight transpose+cvt and x->bf16. 16.6 KB LDS -> ~9 blocks/CU.
// =====================================================================
__global__ __launch_bounds__(256) void prep2_kernel(
    const float* __restrict__ x, const float* __restrict__ ew1, const float* __restrict__ ew2,
    unsigned short* __restrict__ xb, unsigned short* __restrict__ w1t,
    unsigned short* __restrict__ w2t) {
  __shared__ float tile[64][65];
  const int b = blockIdx.x;
  const int tid = threadIdx.x;

  if (b < 6144) {
    const float* src; unsigned short* dst; int R, C, r0, c0;
    if (b < 3072) {
      const int e = b / 1024, w = b % 1024;
      src = ew1 + (size_t)e * 1024 * 4096; dst = w1t + (size_t)e * 4096 * 1024;
      R = 1024; C = 4096; r0 = (w & 15) * 64; c0 = (w >> 4) * 64;
    } else {
      const int bb = b - 3072, e = bb / 1024, w = bb % 1024;
      src = ew2 + (size_t)e * 4096 * 1024; dst = w2t + (size_t)e * 1024 * 4096;
      R = 4096; C = 1024; r0 = (w & 63) * 64; c0 = (w >> 6) * 64;
    }
    const int tr = tid >> 4;
    const int tc = (tid & 15) << 2;
#pragma unroll
    for (int i = 0; i < 4; i++) {
      const int r = tr + i * 16;
      const float4 v = *(const float4*)(src + (size_t)(r0 + r) * C + (c0 + tc));
      tile[r][tc + 0] = v.x; tile[r][tc + 1] = v.y; tile[r][tc + 2] = v.z; tile[r][tc + 3] = v.w;
    }
    __syncthreads();
#pragma unroll
    for (int i = 0; i < 4; i++) {
      const int c = tr + i * 16;
      ushort4 o;
      o.x = f2bf(tile[tc + 0][c]);
      o.y = f2bf(tile[tc + 1][c]);
      o.z = f2bf(tile[tc + 2][c]);
      o.w = f2bf(tile[tc + 3][c]);
      *(ushort4*)(dst + (size_t)(c0 + c) * R + (r0 + tc)) = o;
    }
  } else {
    const float4* xv4 = (const float4*)x;
    const int total = BATCH * IN_DIM / 4;
    for (int i = (b - 6144) * 256 + tid; i < total; i += 512 * 256) {
      const float4 v = xv4[i];
      ushort4 o;
      o.x = f2bf(v.x); o.y = f2bf(v.y); o.z = f2bf(v.z); o.w = f2bf(v.w);
      ((ushort4*)xb)[i] = o;
    }
  }
}

// =====================================================================
// Grouped bf16 GEMM: BM=128, BN=256, BK=32, 8 waves (2M x 4N), 64x64/wave.
// Counted-vmcnt pipeline: NBUF=3, depth D=2, one s_barrier per K-step,
// steady-state s_waitcnt vmcnt(3), vmcnt(0) only at the final iteration.
// (unchanged from rounds 4-5)
// =====================================================================
template <int MODE>
__global__ __launch_bounds__(512, 2) void moe_gemm(
    const unsigned short* __restrict__ Abase, const unsigned short* __restrict__ Ball,
    const float* __restrict__ biasAll, unsigned short* __restrict__ Hout,
    float* __restrict__ Yout, const int* __restrict__ toklist, const int* __restrict__ counts,
    float* __restrict__ tail) {
  constexpr int N  = (MODE == 0) ? HID : OUT_DIM;
  constexpr int K  = (MODE == 0) ? IN_DIM : HID;
  constexpr int NT = K / 32;

  const int tid = threadIdx.x;
  if (MODE == 0 && blockIdx.x == 0 && blockIdx.y == 0 && tid < NE)
    tail[tid] = (float)counts[tid];

  const int c0 = counts[0], c1 = counts[1], c2 = counts[2];
  const int mb0 = (c0 + 127) >> 7, mb1 = (c1 + 127) >> 7, mb2 = (c2 + 127) >> 7;
  const int bx = blockIdx.x;
  int e, mblk;
  if (bx < mb0) { e = 0; mblk = bx; }
  else if (bx < mb0 + mb1) { e = 1; mblk = bx - mb0; }
  else if (bx < mb0 + mb1 + mb2) { e = 2; mblk = bx - mb0 - mb1; }
  else return;
  const int cnt = (e == 0) ? c0 : (e == 1) ? c1 : c2;
  const int m0 = mblk * 128;
  const int n0 = blockIdx.y * 256;
  const int off_e = (e > 0 ? c0 : 0) + (e > 1 ? c1 : 0);
  const unsigned short* Bmat = Ball + (size_t)e * ((size_t)N * K);
  const float* bias = biasAll + (size_t)e * N;

  __shared__ unsigned short Ab[3][128 * 32];   // 8 KB per buf
  __shared__ unsigned short Bb[3][256 * 32];   // 16 KB per buf   (total 72 KB)

  const unsigned short* asrc;
  const unsigned short* bsrc[2];
  unsigned aoff, boff[2];
  {
    const unsigned o = (unsigned)tid * 16u;
    const unsigned p = o ^ (((o >> 6) & 3u) << 4);
    const int row = (int)(o >> 6);
    const int kel = (int)((p & 63u) >> 1);
    aoff = o;
    int slot = m0 + row; if (slot > cnt - 1) slot = cnt - 1;
    const size_t arow = (MODE == 0) ? (size_t)toklist[e * BATCH + slot]
                                    : (size_t)(off_e + slot);
    asrc = Abase + arow * K + kel;
  }
#pragma unroll
  for (int l = 0; l < 2; l++) {
    const unsigned o = l * 8192u + (unsigned)tid * 16u;
    const unsigned p = o ^ (((o >> 6) & 3u) << 4);
    const int row = (int)(o >> 6);
    const int kel = (int)((p & 63u) >> 1);
    boff[l] = o;
    bsrc[l] = Bmat + (size_t)(n0 + row) * K + kel;
  }

  f32x4 acc[4][4];
#pragma unroll
  for (int i = 0; i < 4; i++)
#pragma unroll
    for (int j = 0; j < 4; j++) acc[i][j] = {0.f, 0.f, 0.f, 0.f};

  const int lane = tid & 63;
  const int wave = tid >> 6;
  const int wm = (wave >> 2) * 64;
  const int wn = (wave & 3) * 64;
  const int fr = lane & 15;
  const int fc = lane >> 4;

  auto STAGE = [&](int buf, int kofs) {
    __builtin_amdgcn_global_load_lds((gconst_t*)(asrc + kofs),
                                     (lds_t*)((char*)&Ab[buf][0] + aoff), 16, 0, 0);
#pragma unroll
    for (int l = 0; l < 2; l++)
      __builtin_amdgcn_global_load_lds((gconst_t*)(bsrc[l] + kofs),
                                       (lds_t*)((char*)&Bb[buf][0] + boff[l]), 16, 0, 0);
  };

  STAGE(0, 0);
  STAGE(1, 32);

  int cur = 0;
  for (int t = 0; t < NT; ++t) {
    if (t + 1 < NT) asm volatile("s_waitcnt vmcnt(3)" ::: "memory");
    else            asm volatile("s_waitcnt vmcnt(0)" ::: "memory");
    __builtin_amdgcn_sched_barrier(0);
    __builtin_amdgcn_s_barrier();          // all waves' stage-t landed
    __builtin_amdgcn_sched_barrier(0);
    bf16x8 af[4], bv[4];
#pragma unroll
    for (int m = 0; m < 4; m++) {
      const unsigned row = (unsigned)(wm + m * 16 + fr);
      const unsigned addr = ((row << 6) + (unsigned)(fc << 4)) ^ ((row & 3u) << 4);
      af[m] = *(const bf16x8*)((const char*)&Ab[cur][0] + addr);
    }
#pragma unroll
    for (int n = 0; n < 4; n++) {
      const unsigned row = (unsigned)(wn + n * 16 + fr);
      const unsigned addr = ((row << 6) + (unsigned)(fc << 4)) ^ ((row & 3u) << 4);
      bv[n] = *(const bf16x8*)((const char*)&Bb[cur][0] + addr);
    }
    asm volatile("s_waitcnt lgkmcnt(0)" ::: "memory");
    __builtin_amdgcn_sched_barrier(0);     // rule #18: pin MFMA after the wait
    __builtin_amdgcn_s_setprio(1);
#pragma unroll
    for (int m = 0; m < 4; m++)
#pragma unroll
      for (int n = 0; n < 4; n++)
        acc[m][n] = __builtin_amdgcn_mfma_f32_16x16x32_bf16(af[m], bv[n], acc[m][n], 0, 0, 0);
    __builtin_amdgcn_s_setprio(0);
    if (t + 2 < NT) {
      const int nb = (cur + 2 >= 3) ? cur - 1 : cur + 2;
      STAGE(nb, (t + 2) * 32);
    }
    cur = (cur + 1 == 3) ? 0 : cur + 1;
  }

  // epilogue: C/D layout col=lane&15, row=(lane>>4)*4+reg  [HW-verified m89/m91]
  const int crow = (lane >> 4) * 4;
  const int ccol = lane & 15;
#pragma unroll
  for (int mi = 0; mi < 4; mi++) {
#pragma unroll
    for (int r = 0; r < 4; r++) {
      const int slot = m0 + wm + mi * 16 + crow + r;
      if (slot >= cnt) continue;
      if (MODE == 0) {
        unsigned short* hrow = Hout + (size_t)(off_e + slot) * HID;
#pragma unroll
        for (int ni = 0; ni < 4; ni++) {
          const int n = n0 + wn + ni * 16 + ccol;
          const float v = acc[mi][ni][r] + bias[n];
          hrow[n] = f2bf(fmaxf(v, 0.f));
        }
      } else {
        const int tok = toklist[e * BATCH + slot];
        float* yrow = Yout + (size_t)tok * OUT_DIM;
#pragma unroll
        for (int ni = 0; ni < 4; ni++) {
          const int n = n0 + wn + ni * 16 + ccol;
          yrow[n] = acc[mi][ni][r] + bias[n];
        }
      }
    }
  }
}

extern "C" void kernel_launch(void* const* d_in, const int* in_sizes, int n_in,
                              void* d_out, int out_size, void* d_ws, size_t ws_size,
                              hipStream_t stream) {
  const float* x   = (const float*)d_in[0];
  const float* rw1 = (const float*)d_in[1];
  const float* rb1 = (const float*)d_in[2];
  const float* rw2 = (const float*)d_in[3];
  const float* rb2 = (const float*)d_in[4];
  const float* ew1 = (const float*)d_in[5];
  const float* eb1 = (const float*)d_in[6];
  const float* ew2 = (const float*)d_in[7];
  const float* eb2 = (const float*)d_in[8];
  float* out = (float*)d_out;

  char* ws = (char*)d_ws;
  unsigned short* xb  = (unsigned short*)(ws + XBF_OFF);
  unsigned short* w1t = (unsigned short*)(ws + W1T_OFF);
  unsigned short* w2t = (unsigned short*)(ws + W2T_OFF);
  unsigned short* h   = (unsigned short*)(ws + H_OFF);
  int* counts  = (int*)(ws + META_OFF);
  int* toklist = counts + 16;
  float* tail = out + (size_t)BATCH * OUT_DIM;

  hipMemsetAsync(counts, 0, 64, stream);
  router_kernel<<<512, 256, 0, stream>>>(x, rw1, rb1, rw2, rb2, counts, toklist);
  prep2_kernel<<<6656, 256, 0, stream>>>(x, ew1, ew2, xb, w1t, w2t);
  moe_gemm<0><<<dim3(66, 16), 512, 0, stream>>>(xb, w1t, eb1, h, nullptr, toklist, counts, tail);
  moe_gemm<1><<<dim3(66, 4), 512, 0, stream>>>(h, w2t, eb2, nullptr, out, toklist, counts, tail);
}

// Round 7
// 367.687 us; speedup vs baseline: 2.0314x; 1.0726x over previous
//
#include <hip/hip_runtime.h>
#include <hip/hip_bf16.h>

typedef short bf16x8 __attribute__((ext_vector_type(8)));
typedef float f32x4 __attribute__((ext_vector_type(4)));
typedef __attribute__((address_space(1))) const void gconst_t;
typedef __attribute__((address_space(3))) void lds_t;

#define DEVI __device__ __forceinline__

constexpr int BATCH   = 8192;
constexpr int IN_DIM  = 1024;
constexpr int HID     = 4096;
constexpr int OUT_DIM = 1024;
constexpr int NE      = 3;

// ---- workspace layout (bytes) ----
constexpr size_t XBF_OFF  = 0;                         // x bf16 (hi): 16 MB
constexpr size_t W1T_OFF  = 16777216;                  // W1T bf16 [E][HID][IN]: 24 MB
constexpr size_t W2T_OFF  = W1T_OFF + 25165824;        // W2T bf16 [E][OUT][HID]: 24 MB
constexpr size_t H_OFF    = W2T_OFF + 25165824;        // H bf16 grouped rows: 64 MB
constexpr size_t XLO_OFF  = H_OFF;                     // x_lo ALIASES H: consumed by
                                                       // router_gemm before gemm0 writes H
constexpr size_t META_OFF = H_OFF + 67108864;          // counts[16], toklist[3*8192]
constexpr size_t W3_OFF   = META_OFF + 131072;         // router B [128][3072] bf16: 768 KB

DEVI unsigned short f2bf(float f) {
  __hip_bfloat16 h = __float2bfloat16(f);
  return *reinterpret_cast<unsigned short*>(&h);
}
DEVI float bf2f(unsigned short u) {
  unsigned v = (unsigned)u << 16;
  return __uint_as_float(v);
}

// =====================================================================
// prepA: split-bf16 inputs for the MFMA router (+ xb for gemm0).
//   [0,512)    x -> xb (hi) + xlo:  lo = bf16(x - f32(hi))
//   [512,544)  rw1 [1024][128] -> w3 [128][3072] = [w_hi | w_hi | w_lo]
// =====================================================================
__global__ __launch_bounds__(256) void prepA_kernel(
    const float* __restrict__ x, const float* __restrict__ rw1,
    unsigned short* __restrict__ xb, unsigned short* __restrict__ xlo,
    unsigned short* __restrict__ w3) {
  __shared__ float tile[64][65];
  const int b = blockIdx.x;
  const int tid = threadIdx.x;
  if (b < 512) {
    const float4* xv4 = (const float4*)x;
    const int total = BATCH * IN_DIM / 4;
    for (int i = b * 256 + tid; i < total; i += 512 * 256) {
      const float4 v = xv4[i];
      ushort4 h, l;
      h.x = f2bf(v.x); l.x = f2bf(v.x - bf2f(h.x));
      h.y = f2bf(v.y); l.y = f2bf(v.y - bf2f(h.y));
      h.z = f2bf(v.z); l.z = f2bf(v.z - bf2f(h.z));
      h.w = f2bf(v.w); l.w = f2bf(v.w - bf2f(h.w));
      ((ushort4*)xb)[i] = h;
      ((ushort4*)xlo)[i] = l;
    }
  } else {
    const int w = b - 512;            // 0..31
    const int r0 = (w >> 1) * 64;     // k-tile base
    const int c0 = (w & 1) * 64;      // h-tile base
    const int tr = tid >> 4;
    const int tc = (tid & 15) << 2;
#pragma unroll
    for (int i = 0; i < 4; i++) {
      const int r = tr + i * 16;
      const float4 v = *(const float4*)(rw1 + (size_t)(r0 + r) * 128 + (c0 + tc));
      tile[r][tc + 0] = v.x; tile[r][tc + 1] = v.y; tile[r][tc + 2] = v.z; tile[r][tc + 3] = v.w;
    }
    __syncthreads();
#pragma unroll
    for (int i = 0; i < 4; i++) {
      const int c = tr + i * 16;      // h-local
      ushort4 hi, lo;
      {
        float f;
        f = tile[tc + 0][c]; hi.x = f2bf(f); lo.x = f2bf(f - bf2f(hi.x));
        f = tile[tc + 1][c]; hi.y = f2bf(f); lo.y = f2bf(f - bf2f(hi.y));
        f = tile[tc + 2][c]; hi.z = f2bf(f); lo.z = f2bf(f - bf2f(hi.z));
        f = tile[tc + 3][c]; hi.w = f2bf(f); lo.w = f2bf(f - bf2f(hi.w));
      }
      unsigned short* base = w3 + (size_t)(c0 + c) * 3072 + (r0 + tc);
      *(ushort4*)(base)        = hi;
      *(ushort4*)(base + 1024) = hi;
      *(ushort4*)(base + 2048) = lo;
    }
  }
}

// =====================================================================
// Router GEMM: logits via split-bf16 MFMA, f32-class accuracy.
// M=8192 tokens (64 blocks x BM=128), N=128 hcols, K=3072 effective
// (segments: x_hi@w_hi + x_lo@w_hi + x_hi@w_lo, pre-concat in w3; A base
// pointer switches by segment). BK=32, 4 waves (2M x 2N, 64x64/wave),
// NBUF=3 counted-vmcnt pipeline (proven moe_gemm structure; LPT=4 ->
// steady vmcnt(4)). Epilogue: +b1, relu -> LDS; layer-2 (j ascending,
// same order as rounds 1-6); argmax; atomic bucket.
// =====================================================================
__global__ __launch_bounds__(256) void router_gemm(
    const unsigned short* __restrict__ xhi, const unsigned short* __restrict__ xlo,
    const unsigned short* __restrict__ w3, const float* __restrict__ rb1,
    const float* __restrict__ rw2, const float* __restrict__ rb2,
    int* __restrict__ counts, int* __restrict__ toklist) {
  __shared__ __align__(16) char smem[70656];
  unsigned short* Ab = (unsigned short*)smem;            // [3][128*32] = 24 KB
  unsigned short* Bb = (unsigned short*)(smem + 24576);  // [3][128*32] = 24 KB
  float* rhp  = (float*)smem;                            // [128][132] = 66 KB (epilogue)
  float* lgp  = (float*)(smem + 67584);                  // [128][3]
  float* rw2l = (float*)(smem + 69120);                  // [384]

  const int tid = threadIdx.x;
  const int m0 = blockIdx.x * 128;
  constexpr int NT = 96;   // 3072 / 32

  // staging addresses (same swizzle discipline as moe_gemm: rows are 64 B,
  // LDS dest linear o, global source pre-swizzled p, readers XOR back)
  int tokA[2], kelA[2];
  unsigned aoff[2];
  const unsigned short* bsrc[2];
  unsigned boff[2];
#pragma unroll
  for (int l = 0; l < 2; l++) {
    const unsigned o = l * 4096u + (unsigned)tid * 16u;
    const unsigned p = o ^ (((o >> 6) & 3u) << 4);
    const int row = (int)(o >> 6);            // 0..127
    const int kel = (int)((p & 63u) >> 1);    // 0..31
    aoff[l] = o;
    tokA[l] = m0 + row;
    kelA[l] = kel;
    boff[l] = o;
    bsrc[l] = w3 + (size_t)row * 3072 + kel;
  }

  auto STAGE = [&](int buf, int t) {
    const int seg = t >> 5;                   // 0,1,2
    const int kin = (t & 31) * 32;
    const unsigned short* abase = (seg == 1) ? xlo : xhi;
#pragma unroll
    for (int l = 0; l < 2; l++)
      __builtin_amdgcn_global_load_lds(
          (gconst_t*)(abase + (size_t)tokA[l] * 1024 + kin + kelA[l]),
          (lds_t*)((char*)Ab + buf * 8192 + aoff[l]), 16, 0, 0);
#pragma unroll
    for (int l = 0; l < 2; l++)
      __builtin_amdgcn_global_load_lds(
          (gconst_t*)(bsrc[l] + t * 32),
          (lds_t*)((char*)Bb + buf * 8192 + boff[l]), 16, 0, 0);
  };

  f32x4 acc[4][4];
#pragma unroll
  for (int i = 0; i < 4; i++)
#pragma unroll
    for (int j = 0; j < 4; j++) acc[i][j] = {0.f, 0.f, 0.f, 0.f};

  const int lane = tid & 63;
  const int wave = tid >> 6;
  const int wm = (wave >> 1) * 64;
  const int wn = (wave & 1) * 64;
  const int fr = lane & 15;
  const int fc = lane >> 4;

  STAGE(0, 0);
  STAGE(1, 1);

  int cur = 0;
  for (int t = 0; t < NT; ++t) {
    if (t + 1 < NT) asm volatile("s_waitcnt vmcnt(4)" ::: "memory");
    else            asm volatile("s_waitcnt vmcnt(0)" ::: "memory");
    __builtin_amdgcn_sched_barrier(0);
    __builtin_amdgcn_s_barrier();
    __builtin_amdgcn_sched_barrier(0);
    bf16x8 af[4], bv[4];
#pragma unroll
    for (int m = 0; m < 4; m++) {
      const unsigned row = (unsigned)(wm + m * 16 + fr);
      const unsigned addr = ((row << 6) + (unsigned)(fc << 4)) ^ ((row & 3u) << 4);
      af[m] = *(const bf16x8*)((const char*)Ab + cur * 8192 + addr);
    }
#pragma unroll
    for (int n = 0; n < 4; n++) {
      const unsigned row = (unsigned)(wn + n * 16 + fr);
      const unsigned addr = ((row << 6) + (unsigned)(fc << 4)) ^ ((row & 3u) << 4);
      bv[n] = *(const bf16x8*)((const char*)Bb + cur * 8192 + addr);
    }
    asm volatile("s_waitcnt lgkmcnt(0)" ::: "memory");
    __builtin_amdgcn_sched_barrier(0);
    __builtin_amdgcn_s_setprio(1);
#pragma unroll
    for (int m = 0; m < 4; m++)
#pragma unroll
      for (int n = 0; n < 4; n++)
        acc[m][n] = __builtin_amdgcn_mfma_f32_16x16x32_bf16(af[m], bv[n], acc[m][n], 0, 0, 0);
    __builtin_amdgcn_s_setprio(0);
    if (t + 2 < NT) {
      const int nb = (cur + 2 >= 3) ? cur - 1 : cur + 2;
      STAGE(nb, t + 2);
    }
    cur = (cur + 1 == 3) ? 0 : cur + 1;
  }

  __syncthreads();   // all waves done reading staging LDS; safe to overwrite

  // stage rw2 to LDS
  for (int i = tid; i < 384; i += 256) rw2l[i] = rw2[i];

  // bias + relu -> rhp[tok][h], stride 132 (16B-aligned rows, low conflict)
  const int crow = (lane >> 4) * 4;
  const int ccol = lane & 15;
  float b1v[4];
#pragma unroll
  for (int ni = 0; ni < 4; ni++) b1v[ni] = rb1[wn + ni * 16 + ccol];
#pragma unroll
  for (int mi = 0; mi < 4; mi++) {
#pragma unroll
    for (int r = 0; r < 4; r++) {
      const int tokL = wm + mi * 16 + crow + r;
#pragma unroll
      for (int ni = 0; ni < 4; ni++) {
        const int h = wn + ni * 16 + ccol;
        rhp[tokL * 132 + h] = fmaxf(acc[mi][ni][r] + b1v[ni], 0.f);
      }
    }
  }
  __syncthreads();

  // layer 2: logits[tok][e], j ascending (same order as prior rounds)
#pragma unroll
  for (int pass = 0; pass < 2; ++pass) {
    const int t = tid + pass * 256;
    if (t < 384) {
      const int tok = t / 3, e = t - tok * 3;
      float s = rb2[e];
#pragma unroll 4
      for (int j = 0; j < 128; ++j) s = fmaf(rhp[tok * 132 + j], rw2l[j * 3 + e], s);
      lgp[tok * 3 + e] = s;
    }
  }
  __syncthreads();

  if (tid < 128) {
    const float l0 = lgp[tid * 3], l1 = lgp[tid * 3 + 1], l2 = lgp[tid * 3 + 2];
    int sel = 0; float m = l0;
    if (l1 > m) { m = l1; sel = 1; }
    if (l2 > m) { m = l2; sel = 2; }
    const int slot = atomicAdd(&counts[sel], 1);
    toklist[sel * BATCH + slot] = m0 + tid;
  }
}

// =====================================================================
// prep2: weight transpose+cvt only (x-cvt moved to prepA).
// =====================================================================
__global__ __launch_bounds__(256) void prep2_kernel(
    const float* __restrict__ ew1, const float* __restrict__ ew2,
    unsigned short* __restrict__ w1t, unsigned short* __restrict__ w2t) {
  __shared__ float tile[64][65];
  const int b = blockIdx.x;
  const int tid = threadIdx.x;

  const float* src; unsigned short* dst; int R, C, r0, c0;
  if (b < 3072) {
    const int e = b / 1024, w = b % 1024;
    src = ew1 + (size_t)e * 1024 * 4096; dst = w1t + (size_t)e * 4096 * 1024;
    R = 1024; C = 4096; r0 = (w & 15) * 64; c0 = (w >> 4) * 64;
  } else {
    const int bb = b - 3072, e = bb / 1024, w = bb % 1024;
    src = ew2 + (size_t)e * 4096 * 1024; dst = w2t + (size_t)e * 1024 * 4096;
    R = 4096; C = 1024; r0 = (w & 63) * 64; c0 = (w >> 6) * 64;
  }
  const int tr = tid >> 4;
  const int tc = (tid & 15) << 2;
#pragma unroll
  for (int i = 0; i < 4; i++) {
    const int r = tr + i * 16;
    const float4 v = *(const float4*)(src + (size_t)(r0 + r) * C + (c0 + tc));
    tile[r][tc + 0] = v.x; tile[r][tc + 1] = v.y; tile[r][tc + 2] = v.z; tile[r][tc + 3] = v.w;
  }
  __syncthreads();
#pragma unroll
  for (int i = 0; i < 4; i++) {
    const int c = tr + i * 16;
    ushort4 o;
    o.x = f2bf(tile[tc + 0][c]);
    o.y = f2bf(tile[tc + 1][c]);
    o.z = f2bf(tile[tc + 2][c]);
    o.w = f2bf(tile[tc + 3][c]);
    *(ushort4*)(dst + (size_t)(c0 + c) * R + (r0 + tc)) = o;
  }
}

// =====================================================================
// Grouped bf16 GEMM: BM=128, BN=256, BK=32, 8 waves (2M x 4N), 64x64/wave.
// Counted-vmcnt pipeline: NBUF=3, depth D=2, one s_barrier per K-step,
// steady-state s_waitcnt vmcnt(3), vmcnt(0) only at the final iteration.
// (unchanged from rounds 4-6)
// =====================================================================
template <int MODE>
__global__ __launch_bounds__(512, 2) void moe_gemm(
    const unsigned short* __restrict__ Abase, const unsigned short* __restrict__ Ball,
    const float* __restrict__ biasAll, unsigned short* __restrict__ Hout,
    float* __restrict__ Yout, const int* __restrict__ toklist, const int* __restrict__ counts,
    float* __restrict__ tail) {
  constexpr int N  = (MODE == 0) ? HID : OUT_DIM;
  constexpr int K  = (MODE == 0) ? IN_DIM : HID;
  constexpr int NT = K / 32;

  const int tid = threadIdx.x;
  if (MODE == 0 && blockIdx.x == 0 && blockIdx.y == 0 && tid < NE)
    tail[tid] = (float)counts[tid];

  const int c0 = counts[0], c1 = counts[1], c2 = counts[2];
  const int mb0 = (c0 + 127) >> 7, mb1 = (c1 + 127) >> 7, mb2 = (c2 + 127) >> 7;
  const int bx = blockIdx.x;
  int e, mblk;
  if (bx < mb0) { e = 0; mblk = bx; }
  else if (bx < mb0 + mb1) { e = 1; mblk = bx - mb0; }
  else if (bx < mb0 + mb1 + mb2) { e = 2; mblk = bx - mb0 - mb1; }
  else return;
  const int cnt = (e == 0) ? c0 : (e == 1) ? c1 : c2;
  const int m0 = mblk * 128;
  const int n0 = blockIdx.y * 256;
  const int off_e = (e > 0 ? c0 : 0) + (e > 1 ? c1 : 0);
  const unsigned short* Bmat = Ball + (size_t)e * ((size_t)N * K);
  const float* bias = biasAll + (size_t)e * N;

  __shared__ unsigned short Ab[3][128 * 32];   // 8 KB per buf
  __shared__ unsigned short Bb[3][256 * 32];   // 16 KB per buf   (total 72 KB)

  const unsigned short* asrc;
  const unsigned short* bsrc[2];
  unsigned aoff, boff[2];
  {
    const unsigned o = (unsigned)tid * 16u;
    const unsigned p = o ^ (((o >> 6) & 3u) << 4);
    const int row = (int)(o >> 6);
    const int kel = (int)((p & 63u) >> 1);
    aoff = o;
    int slot = m0 + row; if (slot > cnt - 1) slot = cnt - 1;
    const size_t arow = (MODE == 0) ? (size_t)toklist[e * BATCH + slot]
                                    : (size_t)(off_e + slot);
    asrc = Abase + arow * K + kel;
  }
#pragma unroll
  for (int l = 0; l < 2; l++) {
    const unsigned o = l * 8192u + (unsigned)tid * 16u;
    const unsigned p = o ^ (((o >> 6) & 3u) << 4);
    const int row = (int)(o >> 6);
    const int kel = (int)((p & 63u) >> 1);
    boff[l] = o;
    bsrc[l] = Bmat + (size_t)(n0 + row) * K + kel;
  }

  f32x4 acc[4][4];
#pragma unroll
  for (int i = 0; i < 4; i++)
#pragma unroll
    for (int j = 0; j < 4; j++) acc[i][j] = {0.f, 0.f, 0.f, 0.f};

  const int lane = tid & 63;
  const int wave = tid >> 6;
  const int wm = (wave >> 2) * 64;
  const int wn = (wave & 3) * 64;
  const int fr = lane & 15;
  const int fc = lane >> 4;

  auto STAGE = [&](int buf, int kofs) {
    __builtin_amdgcn_global_load_lds((gconst_t*)(asrc + kofs),
                                     (lds_t*)((char*)&Ab[buf][0] + aoff), 16, 0, 0);
#pragma unroll
    for (int l = 0; l < 2; l++)
      __builtin_amdgcn_global_load_lds((gconst_t*)(bsrc[l] + kofs),
                                       (lds_t*)((char*)&Bb[buf][0] + boff[l]), 16, 0, 0);
  };

  STAGE(0, 0);
  STAGE(1, 32);

  int cur = 0;
  for (int t = 0; t < NT; ++t) {
    if (t + 1 < NT) asm volatile("s_waitcnt vmcnt(3)" ::: "memory");
    else            asm volatile("s_waitcnt vmcnt(0)" ::: "memory");
    __builtin_amdgcn_sched_barrier(0);
    __builtin_amdgcn_s_barrier();          // all waves' stage-t landed
    __builtin_amdgcn_sched_barrier(0);
    bf16x8 af[4], bv[4];
#pragma unroll
    for (int m = 0; m < 4; m++) {
      const unsigned row = (unsigned)(wm + m * 16 + fr);
      const unsigned addr = ((row << 6) + (unsigned)(fc << 4)) ^ ((row & 3u) << 4);
      af[m] = *(const bf16x8*)((const char*)&Ab[cur][0] + addr);
    }
#pragma unroll
    for (int n = 0; n < 4; n++) {
      const unsigned row = (unsigned)(wn + n * 16 + fr);
      const unsigned addr = ((row << 6) + (unsigned)(fc << 4)) ^ ((row & 3u) << 4);
      bv[n] = *(const bf16x8*)((const char*)&Bb[cur][0] + addr);
    }
    asm volatile("s_waitcnt lgkmcnt(0)" ::: "memory");
    __builtin_amdgcn_sched_barrier(0);     // rule #18: pin MFMA after the wait
    __builtin_amdgcn_s_setprio(1);
#pragma unroll
    for (int m = 0; m < 4; m++)
#pragma unroll
      for (int n = 0; n < 4; n++)
        acc[m][n] = __builtin_amdgcn_mfma_f32_16x16x32_bf16(af[m], bv[n], acc[m][n], 0, 0, 0);
    __builtin_amdgcn_s_setprio(0);
    if (t + 2 < NT) {
      const int nb = (cur + 2 >= 3) ? cur - 1 : cur + 2;
      STAGE(nb, (t + 2) * 32);
    }
    cur = (cur + 1 == 3) ? 0 : cur + 1;
  }

  // epilogue: C/D layout col=lane&15, row=(lane>>4)*4+reg  [HW-verified m89/m91]
  const int crow = (lane >> 4) * 4;
  const int ccol = lane & 15;
#pragma unroll
  for (int mi = 0; mi < 4; mi++) {
#pragma unroll
    for (int r = 0; r < 4; r++) {
      const int slot = m0 + wm + mi * 16 + crow + r;
      if (slot >= cnt) continue;
      if (MODE == 0) {
        unsigned short* hrow = Hout + (size_t)(off_e + slot) * HID;
#pragma unroll
        for (int ni = 0; ni < 4; ni++) {
          const int n = n0 + wn + ni * 16 + ccol;
          const float v = acc[mi][ni][r] + bias[n];
          hrow[n] = f2bf(fmaxf(v, 0.f));
        }
      } else {
        const int tok = toklist[e * BATCH + slot];
        float* yrow = Yout + (size_t)tok * OUT_DIM;
#pragma unroll
        for (int ni = 0; ni < 4; ni++) {
          const int n = n0 + wn + ni * 16 + ccol;
          yrow[n] = acc[mi][ni][r] + bias[n];
        }
      }
    }
  }
}

extern "C" void kernel_launch(void* const* d_in, const int* in_sizes, int n_in,
                              void* d_out, int out_size, void* d_ws, size_t ws_size,
                              hipStream_t stream) {
  const float* x   = (const float*)d_in[0];
  const float* rw1 = (const float*)d_in[1];
  const float* rb1 = (const float*)d_in[2];
  const float* rw2 = (const float*)d_in[3];
  const float* rb2 = (const float*)d_in[4];
  const float* ew1 = (const float*)d_in[5];
  const float* eb1 = (const float*)d_in[6];
  const float* ew2 = (const float*)d_in[7];
  const float* eb2 = (const float*)d_in[8];
  float* out = (float*)d_out;

  char* ws = (char*)d_ws;
  unsigned short* xb  = (unsigned short*)(ws + XBF_OFF);
  unsigned short* w1t = (unsigned short*)(ws + W1T_OFF);
  unsigned short* w2t = (unsigned short*)(ws + W2T_OFF);
  unsigned short* h   = (unsigned short*)(ws + H_OFF);
  unsigned short* xlo = (unsigned short*)(ws + XLO_OFF);   // aliases H (see layout)
  int* counts  = (int*)(ws + META_OFF);
  int* toklist = counts + 16;
  unsigned short* w3 = (unsigned short*)(ws + W3_OFF);
  float* tail = out + (size_t)BATCH * OUT_DIM;

  hipMemsetAsync(counts, 0, 64, stream);
  prepA_kernel<<<544, 256, 0, stream>>>(x, rw1, xb, xlo, w3);
  router_gemm<<<64, 256, 0, stream>>>(xb, xlo, w3, rb1, rw2, rb2, counts, toklist);
  prep2_kernel<<<6144, 256, 0, stream>>>(ew1, ew2, w1t, w2t);
  moe_gemm<0><<<dim3(66, 16), 512, 0, stream>>>(xb, w1t, eb1, h, nullptr, toklist, counts, tail);
  moe_gemm<1><<<dim3(66, 4), 512, 0, stream>>>(h, w2t, eb2, nullptr, out, toklist, counts, tail);
}